// Round 26
// baseline (203.905 us; speedup 1.0000x reference)
//
#include <hip/hip_runtime.h>

#pragma clang fp contract(off)

#define NB 16
#define NV 100000
#define NF 200000
#define NP 65536

// XLA ReduceWindowRewriter, base_length = 16:
// 200000 = 12500*16 (exact), then 12500 -> 782 -> 49 -> 4 (sequential).
#define B16 16
#define NW0 12500
#define NW1 782
#define NW2 49
#define NW3 4

// ---------------------------------------------------------------------------
__global__ void detect_kernel(const int* __restrict__ faces, int* __restrict__ flag) {
    __shared__ int any;
    if (threadIdx.x == 0) any = 0;
    __syncthreads();
    int acc = 0;
    for (int i = threadIdx.x; i < 4096; i += blockDim.x)
        acc |= faces[2 * i + 1];
    if (acc) atomicOr(&any, 1);
    __syncthreads();
    if (threadIdx.x == 0) flag[0] = (any == 0) ? 1 : 0;
}

__device__ __forceinline__ void load_face(const int* __restrict__ faces,
                                          long long fidx, int is64,
                                          int& i0, int& i1, int& i2) {
    if (is64) {
        const int* p = faces + fidx * 6;
        i0 = p[0]; i1 = p[2]; i2 = p[4];
    } else {
        const int* p = faces + fidx * 3;
        i0 = p[0]; i1 = p[1]; i2 = p[2];
    }
}

// ---------------------------------------------------------------------------
// Kernel 1 — ROUND-26 KNOB: FMA-CONTRACTED area (TPU VPU fuses mul-sub):
//   cross:  nx = fma(v1y, v2z, -(v1z*v2y))   (first product exact)
//   norm2:  ss = fma(nz, nz, fma(nx, nx, ny*ny))
//   CR sqrt, /2 (exact).
// ---------------------------------------------------------------------------
__global__ void area_kernel(const float* __restrict__ verts,
                            const int* __restrict__ faces,
                            const int* __restrict__ flag,
                            float* __restrict__ area) {
    int gid = blockIdx.x * blockDim.x + threadIdx.x;
    if (gid >= NB * NF) return;
    int is64 = flag[0];
    int b = gid / NF;
    const float* vb = verts + (size_t)b * NV * 3;
    int i0, i1, i2;
    load_face(faces, (long long)gid, is64, i0, i1, i2);
    float ax = vb[3 * i0 + 0], ay = vb[3 * i0 + 1], az = vb[3 * i0 + 2];
    float bx = vb[3 * i1 + 0], by = vb[3 * i1 + 1], bz = vb[3 * i1 + 2];
    float cx = vb[3 * i2 + 0], cy = vb[3 * i2 + 1], cz = vb[3 * i2 + 2];
    float v1x = bx - ax, v1y = by - ay, v1z = bz - az;
    float v2x = cx - ax, v2y = cy - ay, v2z = cz - az;
    float nx = fmaf(v1y, v2z, -(v1z * v2y));
    float ny = fmaf(v1z, v2x, -(v1x * v2z));
    float nz = fmaf(v1x, v2y, -(v1y * v2x));
    float ss = fmaf(nz, nz, fmaf(nx, nx, ny * ny));
    float nrm = sqrtf(ss);
    area[gid] = nrm / 2.0f;
}

// ---------------------------------------------------------------------------
// Stage A: window-16 sequential prefix in place; block sums s0[b][12500].
// ---------------------------------------------------------------------------
__global__ void winscan_kernel(float* __restrict__ cdf, float* __restrict__ s0) {
    int t = blockIdx.x * blockDim.x + threadIdx.x;
    if (t >= NB * NW0) return;
    int b = t / NW0, j = t % NW0;
    float* base = cdf + (size_t)b * NF + (size_t)j * B16;
    float run = 0.0f;
    #pragma unroll
    for (int p = 0; p < B16; ++p) { run = run + base[p]; base[p] = run; }
    s0[(size_t)b * NW0 + j] = run;
}

// ---------------------------------------------------------------------------
// Stage B: per batch, scan s0[12500] with the SAME base-16 structure.
// ---------------------------------------------------------------------------
__global__ void midscan16_kernel(const float* __restrict__ s0g, float* __restrict__ S0g) {
    __shared__ float t0[NW0];
    __shared__ float t1[NW1];
    __shared__ float t2[NW2];
    __shared__ float t3[NW3];
    int b = blockIdx.x;
    for (int i = threadIdx.x; i < NW0; i += blockDim.x)
        t0[i] = s0g[(size_t)b * NW0 + i];
    __syncthreads();
    for (int w = threadIdx.x; w < NW1; w += blockDim.x) {
        int st = w * B16, en = st + B16 < NW0 ? st + B16 : NW0;
        float run = 0.0f;
        for (int p = st; p < en; ++p) { run = run + t0[p]; t0[p] = run; }
        t1[w] = run;
    }
    __syncthreads();
    for (int w = threadIdx.x; w < NW2; w += blockDim.x) {
        int st = w * B16, en = st + B16 < NW1 ? st + B16 : NW1;
        float run = 0.0f;
        for (int p = st; p < en; ++p) { run = run + t1[p]; t1[p] = run; }
        t2[w] = run;
    }
    __syncthreads();
    for (int w = threadIdx.x; w < NW3; w += blockDim.x) {
        int st = w * B16, en = st + B16 < NW2 ? st + B16 : NW2;
        float run = 0.0f;
        for (int p = st; p < en; ++p) { run = run + t2[p]; t2[p] = run; }
        t3[w] = run;
    }
    __syncthreads();
    if (threadIdx.x == 0) {
        float run = 0.0f;
        for (int k = 0; k < NW3; ++k) { run = run + t3[k]; t3[k] = run; }
    }
    __syncthreads();
    for (int i = threadIdx.x; i < NW2; i += blockDim.x) {
        int w = i >> 4;
        float off = (w > 0) ? t3[w - 1] : 0.0f;
        t2[i] = off + t2[i];
    }
    __syncthreads();
    for (int i = threadIdx.x; i < NW1; i += blockDim.x) {
        int w = i >> 4;
        float off = (w > 0) ? t2[w - 1] : 0.0f;
        t1[i] = off + t1[i];
    }
    __syncthreads();
    for (int i = threadIdx.x; i < NW0; i += blockDim.x) {
        int w = i >> 4;
        float off = (w > 0) ? t1[w - 1] : 0.0f;
        t0[i] = off + t0[i];
    }
    __syncthreads();
    for (int i = threadIdx.x; i < NW0; i += blockDim.x)
        S0g[(size_t)b * NW0 + i] = t0[i];
}

// ---------------------------------------------------------------------------
// Stage C: cdf[b][16j+p] = inner_prefix + exclusive(S0)[j]
// ---------------------------------------------------------------------------
__global__ void addoff16_kernel(float* __restrict__ cdf, const float* __restrict__ S0) {
    int i = blockIdx.x * blockDim.x + threadIdx.x;
    int b = blockIdx.y;
    if (i >= NF) return;
    int j = i >> 4;
    float off = (j > 0) ? S0[(size_t)b * NW0 + j - 1] : 0.0f;
    float* p = cdf + (size_t)b * NF + i;
    *p = off + *p;
}

// ---------------------------------------------------------------------------
// Totals snapshot (race-free), then reciprocal-multiply normalize (TPU-style).
// ---------------------------------------------------------------------------
__global__ void save_total_kernel(const float* __restrict__ cdf, float* __restrict__ totals) {
    int b = blockIdx.x * blockDim.x + threadIdx.x;
    if (b < NB) totals[b] = cdf[(size_t)b * NF + NF - 1];
}
__global__ void normalize_kernel(float* __restrict__ cdf, const float* __restrict__ totals) {
    int i = blockIdx.x * blockDim.x + threadIdx.x;
    int b = blockIdx.y;
    if (i >= NF) return;
    float rcp = 1.0f / totals[b];      // CR f32 reciprocal (per batch)
    float* base = cdf + (size_t)b * NF;
    base[i] = base[i] * rcp;           // CR f32 multiply (per element)
}

// ---------------------------------------------------------------------------
// Kernel 3: jnp.searchsorted method='scan' (18 levels, side='left':
// go_left = u <= c[mid]; low=mid; return high). f64 epilogue, stored f32.
// ---------------------------------------------------------------------------
__global__ void sample_kernel(const float* __restrict__ verts,
                              const int* __restrict__ faces,
                              const int* __restrict__ flag,
                              const float* __restrict__ e1,
                              const float* __restrict__ e2,
                              const float* __restrict__ u,
                              const float* __restrict__ cdf,
                              float* __restrict__ out) {
    int gid = blockIdx.x * blockDim.x + threadIdx.x;
    if (gid >= NB * NP) return;
    int is64 = flag[0];
    int b = gid >> 16;           // P = 65536
    const float* c = cdf + (size_t)b * NF;

    float uv = u[gid];
    int low = 0, high = NF;
    #pragma unroll
    for (int it = 0; it < 18; ++it) {      // ceil(log2(200001)) = 18
        int mid = (low + high) >> 1;
        bool go_left = (uv <= c[mid]);
        low  = go_left ? low : mid;
        high = go_left ? mid : high;
    }
    int idx = high < NF - 1 ? high : NF - 1;

    const float* vb = verts + (size_t)b * NV * 3;
    int i0, i1, i2;
    load_face(faces, (long long)b * NF + idx, is64, i0, i1, i2);
    double ax = vb[3 * i0 + 0], ay = vb[3 * i0 + 1], az = vb[3 * i0 + 2];
    double bx = vb[3 * i1 + 0], by = vb[3 * i1 + 1], bz = vb[3 * i1 + 2];
    double cx = vb[3 * i2 + 0], cy = vb[3 * i2 + 1], cz = vb[3 * i2 + 2];

    double v1x = bx - ax, v1y = by - ay, v1z = bz - az;
    double v2x = cx - ax, v2y = cy - ay, v2z = cz - az;
    double nx = v1y * v2z - v1z * v2y;
    double ny = v1z * v2x - v1x * v2z;
    double nz = v1x * v2y - v1y * v2x;
    double ss = (nx * nx + ny * ny) + nz * nz;
    double nrm = sqrt(ss);
    double unx = nx / nrm, uny = ny / nrm, unz = nz / nrm;

    double s = sqrt((double)e1[gid]);
    double t = (double)e2[gid];
    double w0 = 1.0 - s;
    double w1 = (1.0 - t) * s;
    double w2 = t * s;
    double px = (ax * w0 + bx * w1) + cx * w2;
    double py = (ay * w0 + by * w1) + cy * w2;
    double pz = (az * w0 + bz * w1) + cz * w2;

    size_t po = (size_t)gid * 3;
    out[po + 0] = (float)px;
    out[po + 1] = (float)py;
    out[po + 2] = (float)pz;
    size_t no = (size_t)NB * NP * 3 + po;
    out[no + 0] = (float)unx;
    out[no + 1] = (float)uny;
    out[no + 2] = (float)unz;
}

extern "C" void kernel_launch(void* const* d_in, const int* in_sizes, int n_in,
                              void* d_out, int out_size, void* d_ws, size_t ws_size,
                              hipStream_t stream) {
    const float* verts = (const float*)d_in[0];  // fp32
    const int*   faces = (const int*)d_in[1];    // int32 (guarded for int64)
    const float* e1    = (const float*)d_in[2];
    const float* e2    = (const float*)d_in[3];
    const float* u     = (const float*)d_in[4];
    float* out = (float*)d_out;

    char* ws = (char*)d_ws;
    int*   flag   = (int*)ws;                                // 256 B
    float* totals = (float*)(ws + 256);                      // 16 floats
    float* cdf    = (float*)(ws + 512);                      // 12.8 MB
    float* s0     = (float*)(ws + 512 + (size_t)NB * NF * 4);             // 800 KB
    float* S0     = (float*)(ws + 512 + (size_t)NB * NF * 4 + (size_t)NB * NW0 * 4);

    detect_kernel<<<1, 256, 0, stream>>>(faces, flag);

    int nt = 256;
    area_kernel<<<(NB * NF + nt - 1) / nt, nt, 0, stream>>>(verts, faces, flag, cdf);

    winscan_kernel<<<(NB * NW0 + nt - 1) / nt, nt, 0, stream>>>(cdf, s0);
    midscan16_kernel<<<NB, nt, 0, stream>>>(s0, S0);
    {
        dim3 g((NF + nt - 1) / nt, NB);
        addoff16_kernel<<<g, nt, 0, stream>>>(cdf, S0);
    }

    save_total_kernel<<<1, 64, 0, stream>>>(cdf, totals);
    {
        dim3 g((NF + nt - 1) / nt, NB);
        normalize_kernel<<<g, nt, 0, stream>>>(cdf, totals);
    }

    sample_kernel<<<(NB * NP + nt - 1) / nt, nt, 0, stream>>>(verts, faces, flag, e1, e2, u, cdf, out);
}

// Round 27
// 174.126 us; speedup vs baseline: 1.1710x; 1.1710x over previous
//
#include <hip/hip_runtime.h>

#pragma clang fp contract(off)

#define NB 16
#define NV 100000
#define NF 200000
#define NP 65536

// XLA ReduceWindowRewriter, base_length = 16:
// 200000 = 12500*16, then 12500 -> 782 -> 49 -> 4 (sequential windows).
#define B16 16
#define NW0 12500
#define NW1 782
#define NW2 49
#define NW3 4

// XCD-aware swizzle: grid = 16*C blocks, dispatch round-robins blockIdx%8
// across the 8 XCDs. Map block p -> (batch, chunk) with batch = 2*(r&7)+(r>>3),
// r = p&15, chunk = p>>4: batches {2x, 2x+1} land on XCD x, so each XCD's
// 4MB L2 holds only 2 batches' cdf (1.6MB) + verts (2.4MB).
__device__ __forceinline__ void xcd_map(int p, int& batch, int& chunk) {
    int r = p & 15;
    batch = 2 * (r & 7) + (r >> 3);
    chunk = p >> 4;
}

// ---------------------------------------------------------------------------
__global__ void detect_kernel(const int* __restrict__ faces, int* __restrict__ flag) {
    __shared__ int any;
    if (threadIdx.x == 0) any = 0;
    __syncthreads();
    int acc = 0;
    for (int i = threadIdx.x; i < 4096; i += blockDim.x)
        acc |= faces[2 * i + 1];
    if (acc) atomicOr(&any, 1);
    __syncthreads();
    if (threadIdx.x == 0) flag[0] = (any == 0) ? 1 : 0;
}

__device__ __forceinline__ void load_face(const int* __restrict__ faces,
                                          long long fidx, int is64,
                                          int& i0, int& i1, int& i2) {
    if (is64) {
        const int* p = faces + fidx * 6;
        i0 = p[0]; i1 = p[2]; i2 = p[4];
    } else {
        const int* p = faces + fidx * 3;
        i0 = p[0]; i1 = p[1]; i2 = p[2];
    }
}

// ---------------------------------------------------------------------------
// Kernel 1: FMA-contracted area (gold semantics — verified R26):
//   nx = fma(v1y,v2z,-(v1z*v2y)); ss = fma(nz,nz,fma(nx,nx,ny*ny));
//   CR sqrt; /2.   XCD-swizzled grid: 16 batches x 782 chunks.
// ---------------------------------------------------------------------------
__global__ void area_kernel(const float* __restrict__ verts,
                            const int* __restrict__ faces,
                            const int* __restrict__ flag,
                            float* __restrict__ area) {
    int batch, chunk;
    xcd_map(blockIdx.x, batch, chunk);
    int i = chunk * 256 + threadIdx.x;
    if (i >= NF) return;
    int is64 = flag[0];
    size_t gid = (size_t)batch * NF + i;
    const float* vb = verts + (size_t)batch * NV * 3;
    int i0, i1, i2;
    load_face(faces, (long long)gid, is64, i0, i1, i2);
    float ax = vb[3 * i0 + 0], ay = vb[3 * i0 + 1], az = vb[3 * i0 + 2];
    float bx = vb[3 * i1 + 0], by = vb[3 * i1 + 1], bz = vb[3 * i1 + 2];
    float cx = vb[3 * i2 + 0], cy = vb[3 * i2 + 1], cz = vb[3 * i2 + 2];
    float v1x = bx - ax, v1y = by - ay, v1z = bz - az;
    float v2x = cx - ax, v2y = cy - ay, v2z = cz - az;
    float nx = fmaf(v1y, v2z, -(v1z * v2y));
    float ny = fmaf(v1z, v2x, -(v1x * v2z));
    float nz = fmaf(v1x, v2y, -(v1y * v2x));
    float ss = fmaf(nz, nz, fmaf(nx, nx, ny * ny));
    float nrm = sqrtf(ss);
    area[gid] = nrm / 2.0f;
}

// ---------------------------------------------------------------------------
// Stage A: window-16 sequential prefix in place; block sums s0[b][12500].
// XCD-swizzled: 16 batches x 49 chunks of 256 windows.
// ---------------------------------------------------------------------------
__global__ void winscan_kernel(float* __restrict__ cdf, float* __restrict__ s0) {
    int batch, chunk;
    xcd_map(blockIdx.x, batch, chunk);
    int j = chunk * 256 + threadIdx.x;
    if (j >= NW0) return;
    float* base = cdf + (size_t)batch * NF + (size_t)j * B16;
    float run = 0.0f;
    #pragma unroll
    for (int p = 0; p < B16; ++p) { run = run + base[p]; base[p] = run; }
    s0[(size_t)batch * NW0 + j] = run;
}

// ---------------------------------------------------------------------------
// Stage B: per batch, scan s0[12500] with the SAME base-16 structure.
// ---------------------------------------------------------------------------
__global__ void midscan16_kernel(const float* __restrict__ s0g, float* __restrict__ S0g) {
    __shared__ float t0[NW0];
    __shared__ float t1[NW1];
    __shared__ float t2[NW2];
    __shared__ float t3[NW3];
    int b = blockIdx.x;
    for (int i = threadIdx.x; i < NW0; i += blockDim.x)
        t0[i] = s0g[(size_t)b * NW0 + i];
    __syncthreads();
    for (int w = threadIdx.x; w < NW1; w += blockDim.x) {
        int st = w * B16, en = st + B16 < NW0 ? st + B16 : NW0;
        float run = 0.0f;
        for (int p = st; p < en; ++p) { run = run + t0[p]; t0[p] = run; }
        t1[w] = run;
    }
    __syncthreads();
    for (int w = threadIdx.x; w < NW2; w += blockDim.x) {
        int st = w * B16, en = st + B16 < NW1 ? st + B16 : NW1;
        float run = 0.0f;
        for (int p = st; p < en; ++p) { run = run + t1[p]; t1[p] = run; }
        t2[w] = run;
    }
    __syncthreads();
    for (int w = threadIdx.x; w < NW3; w += blockDim.x) {
        int st = w * B16, en = st + B16 < NW2 ? st + B16 : NW2;
        float run = 0.0f;
        for (int p = st; p < en; ++p) { run = run + t2[p]; t2[p] = run; }
        t3[w] = run;
    }
    __syncthreads();
    if (threadIdx.x == 0) {
        float run = 0.0f;
        for (int k = 0; k < NW3; ++k) { run = run + t3[k]; t3[k] = run; }
    }
    __syncthreads();
    for (int i = threadIdx.x; i < NW2; i += blockDim.x) {
        int w = i >> 4;
        float off = (w > 0) ? t3[w - 1] : 0.0f;
        t2[i] = off + t2[i];
    }
    __syncthreads();
    for (int i = threadIdx.x; i < NW1; i += blockDim.x) {
        int w = i >> 4;
        float off = (w > 0) ? t2[w - 1] : 0.0f;
        t1[i] = off + t1[i];
    }
    __syncthreads();
    for (int i = threadIdx.x; i < NW0; i += blockDim.x) {
        int w = i >> 4;
        float off = (w > 0) ? t1[w - 1] : 0.0f;
        t0[i] = off + t0[i];
    }
    __syncthreads();
    for (int i = threadIdx.x; i < NW0; i += blockDim.x)
        S0g[(size_t)b * NW0 + i] = t0[i];
}

// ---------------------------------------------------------------------------
// FUSED Stage C + normalize (bit-exact to the split version):
//   total  = S0[NW0-2] + s0[NW0-1]      (identical add order "off + inner"
//            that addoff16 would produce at element NF-1)
//   rcp    = 1.0f / total               (CR, per batch)
//   cdf[i] = (excl_off + cdf[i]) * rcp  (add then CR multiply — same two
//            roundings as addoff16 followed by normalize)
// XCD-swizzled: 16 batches x 782 chunks.
// ---------------------------------------------------------------------------
__global__ void fused_norm_kernel(float* __restrict__ cdf,
                                  const float* __restrict__ s0,
                                  const float* __restrict__ S0) {
    int batch, chunk;
    xcd_map(blockIdx.x, batch, chunk);
    int i = chunk * 256 + threadIdx.x;
    if (i >= NF) return;
    const float* S0b = S0 + (size_t)batch * NW0;
    float total = S0b[NW0 - 2] + s0[(size_t)batch * NW0 + NW0 - 1];
    float rcp = 1.0f / total;
    int j = i >> 4;
    float off = (j > 0) ? S0b[j - 1] : 0.0f;
    float* p = cdf + (size_t)batch * NF + i;
    *p = (off + *p) * rcp;
}

// ---------------------------------------------------------------------------
// Kernel 3: jnp.searchsorted method='scan' (18 levels, side='left':
// go_left = u <= c[mid]; low=mid; return high). f64 epilogue, stored f32.
// XCD-swizzled: 16 batches x 256 chunks -> per-XCD L2 holds 2 batches.
// ---------------------------------------------------------------------------
__global__ void sample_kernel(const float* __restrict__ verts,
                              const int* __restrict__ faces,
                              const int* __restrict__ flag,
                              const float* __restrict__ e1,
                              const float* __restrict__ e2,
                              const float* __restrict__ u,
                              const float* __restrict__ cdf,
                              float* __restrict__ out) {
    int batch, chunk;
    xcd_map(blockIdx.x, batch, chunk);
    int li = chunk * 256 + threadIdx.x;      // local sample index in [0, NP)
    int b = batch;
    int gid = (b << 16) + li;                // P = 65536
    int is64 = flag[0];
    const float* c = cdf + (size_t)b * NF;

    float uv = u[gid];
    int low = 0, high = NF;
    #pragma unroll
    for (int it = 0; it < 18; ++it) {        // ceil(log2(200001)) = 18
        int mid = (low + high) >> 1;
        bool go_left = (uv <= c[mid]);
        low  = go_left ? low : mid;
        high = go_left ? mid : high;
    }
    int idx = high < NF - 1 ? high : NF - 1;

    const float* vb = verts + (size_t)b * NV * 3;
    int i0, i1, i2;
    load_face(faces, (long long)b * NF + idx, is64, i0, i1, i2);
    double ax = vb[3 * i0 + 0], ay = vb[3 * i0 + 1], az = vb[3 * i0 + 2];
    double bx = vb[3 * i1 + 0], by = vb[3 * i1 + 1], bz = vb[3 * i1 + 2];
    double cx = vb[3 * i2 + 0], cy = vb[3 * i2 + 1], cz = vb[3 * i2 + 2];

    double v1x = bx - ax, v1y = by - ay, v1z = bz - az;
    double v2x = cx - ax, v2y = cy - ay, v2z = cz - az;
    double nx = v1y * v2z - v1z * v2y;
    double ny = v1z * v2x - v1x * v2z;
    double nz = v1x * v2y - v1y * v2x;
    double ss = (nx * nx + ny * ny) + nz * nz;
    double nrm = sqrt(ss);
    double unx = nx / nrm, uny = ny / nrm, unz = nz / nrm;

    double s = sqrt((double)e1[gid]);
    double t = (double)e2[gid];
    double w0 = 1.0 - s;
    double w1 = (1.0 - t) * s;
    double w2 = t * s;
    double px = (ax * w0 + bx * w1) + cx * w2;
    double py = (ay * w0 + by * w1) + cy * w2;
    double pz = (az * w0 + bz * w1) + cz * w2;

    size_t po = (size_t)gid * 3;
    out[po + 0] = (float)px;
    out[po + 1] = (float)py;
    out[po + 2] = (float)pz;
    size_t no = (size_t)NB * NP * 3 + po;
    out[no + 0] = (float)unx;
    out[no + 1] = (float)uny;
    out[no + 2] = (float)unz;
}

extern "C" void kernel_launch(void* const* d_in, const int* in_sizes, int n_in,
                              void* d_out, int out_size, void* d_ws, size_t ws_size,
                              hipStream_t stream) {
    const float* verts = (const float*)d_in[0];  // fp32
    const int*   faces = (const int*)d_in[1];    // int32 (guarded for int64)
    const float* e1    = (const float*)d_in[2];
    const float* e2    = (const float*)d_in[3];
    const float* u     = (const float*)d_in[4];
    float* out = (float*)d_out;

    char* ws = (char*)d_ws;
    int*   flag = (int*)ws;                                  // 256 B
    float* cdf  = (float*)(ws + 512);                        // 12.8 MB
    float* s0   = (float*)(ws + 512 + (size_t)NB * NF * 4);               // 800 KB
    float* S0   = (float*)(ws + 512 + (size_t)NB * NF * 4 + (size_t)NB * NW0 * 4);

    detect_kernel<<<1, 256, 0, stream>>>(faces, flag);

    // area: 16 batches x 782 chunks (XCD-swizzled)
    area_kernel<<<16 * 782, 256, 0, stream>>>(verts, faces, flag, cdf);

    // winscan: 16 batches x 49 chunks (XCD-swizzled)
    winscan_kernel<<<16 * 49, 256, 0, stream>>>(cdf, s0);

    midscan16_kernel<<<NB, 256, 0, stream>>>(s0, S0);

    // fused addoff + normalize: 16 batches x 782 chunks (XCD-swizzled)
    fused_norm_kernel<<<16 * 782, 256, 0, stream>>>(cdf, s0, S0);

    // sample: 16 batches x 256 chunks (XCD-swizzled)
    sample_kernel<<<16 * 256, 256, 0, stream>>>(verts, faces, flag, e1, e2, u, cdf, out);
}